// Round 11
// baseline (11514.285 us; speedup 1.0000x reference)
//
#include <hip/hip_runtime.h>
#include <hip/hip_bf16.h>
#include <cstdint>
#include <cstddef>

// Problem constants: N=32768, D=2048, H=4096, E=8, T = N/E = 4096.
#define NTOK 32768
#define DDIM 2048
#define HDIM 4096
#define NEXP 8
#define TTOK 4096

typedef __attribute__((ext_vector_type(8))) __bf16 bf16x8;
typedef __attribute__((ext_vector_type(4))) float f32x4;

#define MFMA_BF16(a, b, c) __builtin_amdgcn_mfma_f32_16x16x32_bf16((a), (b), (c), 0, 0, 0)
#define SBAR() __builtin_amdgcn_s_barrier()
#define SCHED0() __builtin_amdgcn_sched_barrier(0)
#define WAIT_VM(n) asm volatile("s_waitcnt vmcnt(" #n ")" ::: "memory")
#define WAIT_LGKM0() asm volatile("s_waitcnt lgkmcnt(0)" ::: "memory")

__device__ __forceinline__ unsigned short f2bf(float f) {
  unsigned int u = __builtin_bit_cast(unsigned int, f);
  u += 0x7FFFu + ((u >> 16) & 1u);   // round-to-nearest-even
  return (unsigned short)(u >> 16);
}

// ---------------- f32 -> bf16 convert (vectorized, grid-stride) ----------------
__global__ __launch_bounds__(256) void cvt_kernel(const float* __restrict__ src,
                                                  unsigned short* __restrict__ dst,
                                                  long n4) {
  long i = (long)blockIdx.x * blockDim.x + threadIdx.x;
  long stride = (long)gridDim.x * blockDim.x;
  const float4* s4 = (const float4*)src;
  ushort4* d4 = (ushort4*)dst;
  for (; i < n4; i += stride) {
    float4 v = s4[i];
    ushort4 o;
    o.x = f2bf(v.x); o.y = f2bf(v.y); o.z = f2bf(v.z); o.w = f2bf(v.w);
    d4[i] = o;
  }
}

// ------------- transpose w_down (E,H,D) f32 -> (E,D,H) bf16 -------------
__global__ __launch_bounds__(256) void transpose_wd(const float* __restrict__ w,
                                                    unsigned short* __restrict__ wt) {
  __shared__ unsigned short tile[64][66];
  const int e = blockIdx.z;
  const int h0 = blockIdx.y * 64;
  const int d0 = blockIdx.x * 64;
  const float* we = w + (size_t)e * HDIM * DDIM;
  unsigned short* wte = wt + (size_t)e * DDIM * HDIM;
  const int t = threadIdx.x;
  const int r = t >> 4;
  const int c4 = (t & 15) * 4;
#pragma unroll
  for (int p = 0; p < 4; ++p) {
    int h = r + p * 16;
    float4 v = *(const float4*)(we + (size_t)(h0 + h) * DDIM + d0 + c4);
    tile[h][c4 + 0] = f2bf(v.x);
    tile[h][c4 + 1] = f2bf(v.y);
    tile[h][c4 + 2] = f2bf(v.z);
    tile[h][c4 + 3] = f2bf(v.w);
  }
  __syncthreads();
#pragma unroll
  for (int p = 0; p < 4; ++p) {
    int d = r + p * 16;
    ushort4 o;
    o.x = tile[c4 + 0][d];
    o.y = tile[c4 + 1][d];
    o.z = tile[c4 + 2][d];
    o.w = tile[c4 + 3][d];
    *(ushort4*)(wte + (size_t)(d0 + d) * HDIM + h0 + c4) = o;
  }
}

// ------------- staging: 256 rows x 32 bf16 (BK=32), 512 threads x 2 loads -------------
// LDS dest linear (global_load_lds). Row = 64 B = 4 granules of 16 B. Swizzle via
// inverse-XOR on the GLOBAL source granule (rule #21): LDS granule (r,c) <- global
// granule (r, c ^ ((r>>1)&3)); reads apply the same XOR. Pairs of rows share a
// position so a 16-row column read spreads over 4 positions x 2 bank-halves.
__device__ __forceinline__ void stage256x32(const unsigned short* __restrict__ g0,
                                            size_t stride_elems,
                                            unsigned short* lds, int tid) {
#pragma unroll
  for (int i = 0; i < 2; ++i) {
    int gi = i * 512 + tid;          // granule 0..1023; r = row 0..255, c = 0..3
    int r = gi >> 2;
    int c = gi & 3;
    const unsigned short* src = g0 + (size_t)r * stride_elems + ((c ^ ((r >> 1) & 3)) << 3);
    __builtin_amdgcn_global_load_lds(
        (const __attribute__((address_space(1))) unsigned int*)src,
        (__attribute__((address_space(3))) unsigned int*)(lds + (size_t)gi * 8),
        16, 0, 0);
  }
}

__device__ __forceinline__ bf16x8 read_frag32(const unsigned short* lds, int row, int cg) {
  return *(const bf16x8*)(lds + row * 32 + ((cg ^ ((row >> 1) & 3)) << 3));
}

// ------------- GEMM1 + SwiGLU: 256-tok x 256-h tile, BK=32, full dbuf, Nrep=4 -------------
// 8 waves = 2M x 4N; wave = 128 tok x 64 h for BOTH up and gate.
// acc = 8x(4+4) f32x4 = 256 regs; reads 16 KB per 64 MFMA/wave/tile (0.25 KB/MFMA,
// -33% LDS vs r5) -> MFMA becomes the binding pipe (2370 vs 1408 cyc/tile).
// LDS: A 2x16KB + B 2x32KB = 96 KiB. Loop: vmcnt(6)+SBAR -> 16 ds_read + 64 MFMA ->
// lgkm0+SBAR -> stage(t+2) [6 loads]. Counted vmcnt keeps a 2-tile pipeline.
__global__ __launch_bounds__(512) void gemm1_swiglu(
    const unsigned short* __restrict__ Xb,
    const unsigned short* __restrict__ Wb,
    unsigned short* __restrict__ Hid) {
  __shared__ unsigned short sA[2][256 * 32];   // 32 KiB
  __shared__ unsigned short sB[2][512 * 32];   // 64 KiB  [u 0-255 ; g 256-511]
  const int bn = blockIdx.x;   // h tile 0..15 (256 wide)
  const int bm = blockIdx.y;   // token tile 0..15 (256 wide)
  const int e  = blockIdx.z;
  const unsigned short* Xe = Xb + ((size_t)e * TTOK + bm * 256) * DDIM;
  const unsigned short* Wu = Wb + ((size_t)e * 2 * HDIM + (size_t)bn * 256) * DDIM;
  const unsigned short* Wg = Wu + (size_t)HDIM * DDIM;
  const int tid = threadIdx.x;
  const int lane = tid & 63;
  const int wid = tid >> 6;
  const int wm = (wid & 1) * 128;   // tok base within 256
  const int wn = (wid >> 1) * 64;   // h base within 256
  const int lr = lane & 15;
  const int lk = lane >> 4;         // granule 0..3 (K=32 -> one MFMA-K per tile)

  f32x4 au[8][4], ag[8][4];
#pragma unroll
  for (int i = 0; i < 8; ++i)
#pragma unroll
    for (int j = 0; j < 4; ++j) {
      au[i][j] = f32x4{0.f, 0.f, 0.f, 0.f};
      ag[i][j] = f32x4{0.f, 0.f, 0.f, 0.f};
    }

  auto stage_tile = [&](int t) {   // 6 loads/thread
    const int buf = t & 1;
    stage256x32(Xe + t * 32, DDIM, (unsigned short*)sA[buf], tid);
    stage256x32(Wu + t * 32, DDIM, (unsigned short*)sB[buf], tid);
    stage256x32(Wg + t * 32, DDIM, (unsigned short*)sB[buf] + 256 * 32, tid);
  };

  stage_tile(0);
  stage_tile(1);

  const int NT = DDIM / 32;   // 64
  for (int t = 0; t < NT; ++t) {
    if (t + 1 < NT) { WAIT_VM(6); } else { WAIT_VM(0); }
    SBAR();
    SCHED0();
    const unsigned short* A = sA[t & 1];
    const unsigned short* B = sB[t & 1];
    bf16x8 a[8], bu[4], bg[4];
#pragma unroll
    for (int mi = 0; mi < 8; ++mi) a[mi] = read_frag32(A, wm + mi * 16 + lr, lk);
#pragma unroll
    for (int ni = 0; ni < 4; ++ni) bu[ni] = read_frag32(B, wn + ni * 16 + lr, lk);
#pragma unroll
    for (int ni = 0; ni < 4; ++ni) bg[ni] = read_frag32(B, 256 + wn + ni * 16 + lr, lk);
    __builtin_amdgcn_s_setprio(1);
#pragma unroll
    for (int mi = 0; mi < 8; ++mi)
#pragma unroll
      for (int ni = 0; ni < 4; ++ni) {
        au[mi][ni] = MFMA_BF16(a[mi], bu[ni], au[mi][ni]);
        ag[mi][ni] = MFMA_BF16(a[mi], bg[ni], ag[mi][ni]);
      }
    __builtin_amdgcn_s_setprio(0);
    SCHED0();
    WAIT_LGKM0();
    SBAR();                 // all waves done reading buf[t&1]
    SCHED0();
    if (t + 2 < NT) stage_tile(t + 2);
    SCHED0();
  }

  // epilogue: hidden = up * silu(gate); C layout col=lane&15, row=(lane>>4)*4+reg
  unsigned short* He = Hid + ((size_t)e * TTOK + bm * 256) * HDIM + (size_t)bn * 256;
#pragma unroll
  for (int mi = 0; mi < 8; ++mi)
#pragma unroll
    for (int ni = 0; ni < 4; ++ni)
#pragma unroll
      for (int r = 0; r < 4; ++r) {
        int row = wm + mi * 16 + lk * 4 + r;
        int col = wn + ni * 16 + lr;
        float up = au[mi][ni][r];
        float gv = ag[mi][ni][r];
        He[(size_t)row * HDIM + col] = f2bf(up * gv / (1.f + __expf(-gv)));
      }
}

// ------------- GEMM2: out = hidden @ w_downT, 256-tok x 512-d tile, BK=32 -------------
// 8 waves = 2M x 4N; wave = 128 tok x 128 d; acc 8x8 f32x4 = 256 regs.
// Same staging/swizzle/pipeline as gemm1. LDS 96 KiB. NT = 4096/32 = 128.
__global__ __launch_bounds__(512) void gemm2_down(
    const unsigned short* __restrict__ Hid,
    const unsigned short* __restrict__ WdT,
    float* __restrict__ Out) {
  __shared__ unsigned short sA[2][256 * 32];   // 32 KiB
  __shared__ unsigned short sB[2][512 * 32];   // 64 KiB
  const int bn = blockIdx.x;   // d tile 0..3 (512 wide)
  const int bm = blockIdx.y;   // token tile 0..15 (256 wide)
  const int e  = blockIdx.z;
  const unsigned short* Ae = Hid + ((size_t)e * TTOK + bm * 256) * HDIM;
  const unsigned short* Be = WdT + ((size_t)e * DDIM + (size_t)bn * 512) * HDIM;
  const int tid = threadIdx.x;
  const int lane = tid & 63;
  const int wid = tid >> 6;
  const int wm = (wid & 1) * 128;    // tok base within 256
  const int wn = (wid >> 1) * 128;   // d base within 512
  const int lr = lane & 15;
  const int lk = lane >> 4;

  f32x4 acc[8][8];
#pragma unroll
  for (int i = 0; i < 8; ++i)
#pragma unroll
    for (int j = 0; j < 8; ++j) acc[i][j] = f32x4{0.f, 0.f, 0.f, 0.f};

  auto stage_tile = [&](int t) {   // 6 loads/thread
    const int buf = t & 1;
    stage256x32(Ae + t * 32, HDIM, (unsigned short*)sA[buf], tid);
    stage256x32(Be + t * 32, HDIM, (unsigned short*)sB[buf], tid);
    stage256x32(Be + (size_t)256 * HDIM + t * 32, HDIM, (unsigned short*)sB[buf] + 256 * 32, tid);
  };

  stage_tile(0);
  stage_tile(1);

  const int NT = HDIM / 32;   // 128
  for (int t = 0; t < NT; ++t) {
    if (t + 1 < NT) { WAIT_VM(6); } else { WAIT_VM(0); }
    SBAR();
    SCHED0();
    const unsigned short* A = sA[t & 1];
    const unsigned short* B = sB[t & 1];
    bf16x8 a[8], b[8];
#pragma unroll
    for (int mi = 0; mi < 8; ++mi) a[mi] = read_frag32(A, wm + mi * 16 + lr, lk);
#pragma unroll
    for (int ni = 0; ni < 8; ++ni) b[ni] = read_frag32(B, wn + ni * 16 + lr, lk);
    __builtin_amdgcn_s_setprio(1);
#pragma unroll
    for (int mi = 0; mi < 8; ++mi)
#pragma unroll
      for (int ni = 0; ni < 8; ++ni)
        acc[mi][ni] = MFMA_BF16(a[mi], b[ni], acc[mi][ni]);
    __builtin_amdgcn_s_setprio(0);
    SCHED0();
    WAIT_LGKM0();
    SBAR();
    SCHED0();
    if (t + 2 < NT) stage_tile(t + 2);
    SCHED0();
  }

  float* Oe = Out + ((size_t)e * TTOK + bm * 256) * DDIM + (size_t)bn * 512;
#pragma unroll
  for (int mi = 0; mi < 8; ++mi)
#pragma unroll
    for (int ni = 0; ni < 8; ++ni)
#pragma unroll
      for (int r = 0; r < 4; ++r) {
        int row = wm + mi * 16 + lk * 4 + r;
        int col = wn + ni * 16 + lr;
        Oe[(size_t)row * DDIM + col] = acc[mi][ni][r];
      }
}

extern "C" void kernel_launch(void* const* d_in, const int* in_sizes, int n_in,
                              void* d_out, int out_size, void* d_ws, size_t ws_size,
                              hipStream_t stream) {
  const float* x = (const float*)d_in[0];
  const float* wug = (const float*)d_in[1];
  const float* wd = (const float*)d_in[2];
  float* out = (float*)d_out;

  unsigned short* xb   = (unsigned short*)d_ws;                    // 32768*2048
  unsigned short* wugb = xb   + (size_t)NTOK * DDIM;               // 8*8192*2048
  unsigned short* wdT  = wugb + (size_t)NEXP * 2 * HDIM * DDIM;    // 8*2048*4096
  unsigned short* hid  = wdT  + (size_t)NEXP * DDIM * HDIM;        // 8*4096*4096

  cvt_kernel<<<4096, 256, 0, stream>>>(x, xb, (long)NTOK * DDIM / 4);
  cvt_kernel<<<4096, 256, 0, stream>>>(wug, wugb, (long)NEXP * 2 * HDIM * DDIM / 4);
  transpose_wd<<<dim3(DDIM / 64, HDIM / 64, NEXP), 256, 0, stream>>>(wd, wdT);
  gemm1_swiglu<<<dim3(HDIM / 256, TTOK / 256, NEXP), 512, 0, stream>>>(xb, wugb, hid);
  gemm2_down<<<dim3(DDIM / 512, TTOK / 256, NEXP), 512, 0, stream>>>(hid, wdT, out);
}

// Round 12
// 1875.149 us; speedup vs baseline: 6.1405x; 6.1405x over previous
//
#include <hip/hip_runtime.h>
#include <hip/hip_bf16.h>
#include <cstdint>
#include <cstddef>

// Problem constants: N=32768, D=2048, H=4096, E=8, T = N/E = 4096.
#define NTOK 32768
#define DDIM 2048
#define HDIM 4096
#define NEXP 8
#define TTOK 4096

typedef __attribute__((ext_vector_type(8))) __bf16 bf16x8;
typedef __attribute__((ext_vector_type(4))) float f32x4;

#define MFMA_BF16(a, b, c) __builtin_amdgcn_mfma_f32_16x16x32_bf16((a), (b), (c), 0, 0, 0)
#define SBAR() __builtin_amdgcn_s_barrier()
#define SCHED0() __builtin_amdgcn_sched_barrier(0)
#define WAIT_VM(n) asm volatile("s_waitcnt vmcnt(" #n ")" ::: "memory")
#define WAIT_LGKM0() asm volatile("s_waitcnt lgkmcnt(0)" ::: "memory")

__device__ __forceinline__ unsigned short f2bf(float f) {
  unsigned int u = __builtin_bit_cast(unsigned int, f);
  u += 0x7FFFu + ((u >> 16) & 1u);   // round-to-nearest-even
  return (unsigned short)(u >> 16);
}

// ---------------- f32 -> bf16 convert (vectorized, grid-stride) ----------------
__global__ __launch_bounds__(256) void cvt_kernel(const float* __restrict__ src,
                                                  unsigned short* __restrict__ dst,
                                                  long n4) {
  long i = (long)blockIdx.x * blockDim.x + threadIdx.x;
  long stride = (long)gridDim.x * blockDim.x;
  const float4* s4 = (const float4*)src;
  ushort4* d4 = (ushort4*)dst;
  for (; i < n4; i += stride) {
    float4 v = s4[i];
    ushort4 o;
    o.x = f2bf(v.x); o.y = f2bf(v.y); o.z = f2bf(v.z); o.w = f2bf(v.w);
    d4[i] = o;
  }
}

// ------------- transpose w_down (E,H,D) f32 -> (E,D,H) bf16 -------------
__global__ __launch_bounds__(256) void transpose_wd(const float* __restrict__ w,
                                                    unsigned short* __restrict__ wt) {
  __shared__ unsigned short tile[64][66];
  const int e = blockIdx.z;
  const int h0 = blockIdx.y * 64;
  const int d0 = blockIdx.x * 64;
  const float* we = w + (size_t)e * HDIM * DDIM;
  unsigned short* wte = wt + (size_t)e * DDIM * HDIM;
  const int t = threadIdx.x;
  const int r = t >> 4;
  const int c4 = (t & 15) * 4;
#pragma unroll
  for (int p = 0; p < 4; ++p) {
    int h = r + p * 16;
    float4 v = *(const float4*)(we + (size_t)(h0 + h) * DDIM + d0 + c4);
    tile[h][c4 + 0] = f2bf(v.x);
    tile[h][c4 + 1] = f2bf(v.y);
    tile[h][c4 + 2] = f2bf(v.z);
    tile[h][c4 + 3] = f2bf(v.w);
  }
  __syncthreads();
#pragma unroll
  for (int p = 0; p < 4; ++p) {
    int d = r + p * 16;
    ushort4 o;
    o.x = tile[c4 + 0][d];
    o.y = tile[c4 + 1][d];
    o.z = tile[c4 + 2][d];
    o.w = tile[c4 + 3][d];
    *(ushort4*)(wte + (size_t)(d0 + d) * HDIM + h0 + c4) = o;
  }
}

// ------------- staging: half-tile = 128 rows x 64 bf16, 512 threads x 2 loads -------------
// LDS dest linear; swizzle via inverse-XOR on the GLOBAL source granule (rule #21).
// Proven 0 bank conflicts (rounds 1-8).
__device__ __forceinline__ void stage_half(const unsigned short* __restrict__ g0,
                                           size_t stride_elems,
                                           unsigned short* lds, int tid) {
#pragma unroll
  for (int i = 0; i < 2; ++i) {
    int gi = i * 512 + tid;          // granule 0..1023; r = row 0..127, c = 0..7
    int r = gi >> 3;
    int c = gi & 7;
    const unsigned short* src = g0 + (size_t)r * stride_elems + ((c ^ (r & 7)) << 3);
    __builtin_amdgcn_global_load_lds(
        (const __attribute__((address_space(1))) unsigned int*)src,
        (__attribute__((address_space(3))) unsigned int*)(lds + (size_t)gi * 8),
        16, 0, 0);
  }
}

__device__ __forceinline__ bf16x8 read_frag(const unsigned short* lds, int row, int cg) {
  return *(const bf16x8*)(lds + row * 64 + ((cg ^ (row & 7)) << 3));
}

// ------------- GEMM1 + SwiGLU: 256-tok x 128-h tile, m201-faithful 8-phase -------------
// 8 waves = 2M x 4N; wave owns 128 tok x 32 h for BOTH up and gate.
// 2 K-tiles per iteration (T even -> buf0, T+1 -> buf1); 8 phases, each:
//   {ds-read quadrant operands ; stage EXACTLY 1 half-tile ; SBAR ; lgkm0 ; 16 MFMA ; SBAR}
// Stage rolling order (region staged the phase after its last LDS-reader closed):
//   ph1: A-hi(T+1)  ph2: Bu(T+2)  ph3: Bg(T+2)  ph4: A-lo(T+2)+vmcnt(6)
//   ph5: A-hi(T+2)  ph6: Bu(T+3)  ph7: Bg(T+3)  ph8: A-lo(T+3)+vmcnt(6)
// vmcnt(6) = 3 half-tiles x 2 loads in flight; folded into ph4/ph8 (no extra sync region).
__global__ __launch_bounds__(512, 2) void gemm1_swiglu(
    const unsigned short* __restrict__ Xb,
    const unsigned short* __restrict__ Wb,
    unsigned short* __restrict__ Hid) {
  __shared__ unsigned short sA[2][256 * 64];   // 64 KiB  (rows: lo 0-127, hi 128-255)
  __shared__ unsigned short sB[2][256 * 64];   // 64 KiB  (u 0-127 ; g 128-255)
  const int e = blockIdx.z;
  const int bm = blockIdx.y;   // token tile (256)
  const int bn = blockIdx.x;   // h tile (128)
  const unsigned short* Xe = Xb + ((size_t)e * TTOK + bm * 256) * DDIM;
  const unsigned short* Wu = Wb + ((size_t)e * 2 * HDIM + (size_t)bn * 128) * DDIM;
  const unsigned short* Wg = Wu + (size_t)HDIM * DDIM;
  const int tid = threadIdx.x;
  const int lane = tid & 63;
  const int wid = tid >> 6;
  const int wm = (wid & 1) * 128;   // M-half rows
  const int wn = (wid >> 1) * 32;   // h cols within 128
  const int lr = lane & 15;
  const int lk = lane >> 4;

  f32x4 au[8][2], ag[8][2];
#pragma unroll
  for (int i = 0; i < 8; ++i)
#pragma unroll
    for (int j = 0; j < 2; ++j) {
      au[i][j] = f32x4{0.f, 0.f, 0.f, 0.f};
      ag[i][j] = f32x4{0.f, 0.f, 0.f, 0.f};
    }

  auto stAlo = [&](int t) { stage_half(Xe + t * 64, DDIM, (unsigned short*)sA[t & 1], tid); };
  auto stAhi = [&](int t) { stage_half(Xe + (size_t)128 * DDIM + t * 64, DDIM,
                                       (unsigned short*)sA[t & 1] + 128 * 64, tid); };
  auto stBu  = [&](int t) { stage_half(Wu + t * 64, DDIM, (unsigned short*)sB[t & 1], tid); };
  auto stBg  = [&](int t) { stage_half(Wg + t * 64, DDIM, (unsigned short*)sB[t & 1] + 128 * 64, tid); };

  // prologue: tile0 fully, tile1 minus A-hi (ph1 of j=0 stages A-hi(1))
  stBu(0); stBg(0); stAlo(0); stAhi(0);
  stBu(1); stBg(1); stAlo(1);
  WAIT_VM(6); SBAR(); SCHED0();

  const int NT = DDIM / 64;   // 32
  for (int j = 0; j < NT / 2; ++j) {
    const int T = 2 * j;
    const bool last = (T + 2 >= NT);
    const unsigned short* A0 = sA[0];
    const unsigned short* B0 = sB[0];
    const unsigned short* A1 = sA[1];
    const unsigned short* B1 = sB[1];
    bf16x8 a0[4][2], a1[4][2], bu[2][2], bg[2][2];

    // ================= K-tile T (buf0) =================
    // ph1: read a0(8), bu(4); stage A-hi(T+1); MFMA (m0,u)
#pragma unroll
    for (int mi = 0; mi < 4; ++mi)
#pragma unroll
      for (int kh = 0; kh < 2; ++kh)
        a0[mi][kh] = read_frag(A0, wm + mi * 16 + lr, kh * 4 + lk);
#pragma unroll
    for (int ni = 0; ni < 2; ++ni)
#pragma unroll
      for (int kh = 0; kh < 2; ++kh)
        bu[ni][kh] = read_frag(B0, wn + ni * 16 + lr, kh * 4 + lk);
    stAhi(T + 1);
    SCHED0(); SBAR(); WAIT_LGKM0(); SCHED0();
    __builtin_amdgcn_s_setprio(1);
#pragma unroll
    for (int kh = 0; kh < 2; ++kh)
#pragma unroll
      for (int mi = 0; mi < 4; ++mi)
#pragma unroll
        for (int ni = 0; ni < 2; ++ni)
          au[mi][ni] = MFMA_BF16(a0[mi][kh], bu[ni][kh], au[mi][ni]);
    __builtin_amdgcn_s_setprio(0);
    SCHED0(); SBAR();
    // ph2: read bg(4); stage Bu(T+2); MFMA (m0,g)
#pragma unroll
    for (int ni = 0; ni < 2; ++ni)
#pragma unroll
      for (int kh = 0; kh < 2; ++kh)
        bg[ni][kh] = read_frag(B0, 128 + wn + ni * 16 + lr, kh * 4 + lk);
    if (!last) stBu(T + 2);
    SCHED0(); SBAR(); WAIT_LGKM0(); SCHED0();
    __builtin_amdgcn_s_setprio(1);
#pragma unroll
    for (int kh = 0; kh < 2; ++kh)
#pragma unroll
      for (int mi = 0; mi < 4; ++mi)
#pragma unroll
        for (int ni = 0; ni < 2; ++ni)
          ag[mi][ni] = MFMA_BF16(a0[mi][kh], bg[ni][kh], ag[mi][ni]);
    __builtin_amdgcn_s_setprio(0);
    SCHED0(); SBAR();
    // ph3: read a1(8); stage Bg(T+2); MFMA (m1,u)
#pragma unroll
    for (int mi = 0; mi < 4; ++mi)
#pragma unroll
      for (int kh = 0; kh < 2; ++kh)
        a1[mi][kh] = read_frag(A0, wm + 64 + mi * 16 + lr, kh * 4 + lk);
    if (!last) stBg(T + 2);
    SCHED0(); SBAR(); WAIT_LGKM0(); SCHED0();
    __builtin_amdgcn_s_setprio(1);
#pragma unroll
    for (int kh = 0; kh < 2; ++kh)
#pragma unroll
      for (int mi = 0; mi < 4; ++mi)
#pragma unroll
        for (int ni = 0; ni < 2; ++ni)
          au[4 + mi][ni] = MFMA_BF16(a1[mi][kh], bu[ni][kh], au[4 + mi][ni]);
    __builtin_amdgcn_s_setprio(0);
    SCHED0(); SBAR();
    // ph4: stage A-lo(T+2); vmcnt(6 | 0 at tail); MFMA (m1,g)
    if (!last) stAlo(T + 2);
    SCHED0();
    if (last) { WAIT_VM(0); } else { WAIT_VM(6); }
    SBAR(); SCHED0();
    __builtin_amdgcn_s_setprio(1);
#pragma unroll
    for (int kh = 0; kh < 2; ++kh)
#pragma unroll
      for (int mi = 0; mi < 4; ++mi)
#pragma unroll
        for (int ni = 0; ni < 2; ++ni)
          ag[4 + mi][ni] = MFMA_BF16(a1[mi][kh], bg[ni][kh], ag[4 + mi][ni]);
    __builtin_amdgcn_s_setprio(0);
    SCHED0(); SBAR();

    // ================= K-tile T+1 (buf1) =================
    // ph5: read a0(8), bu(4); stage A-hi(T+2); MFMA (m0,u)
#pragma unroll
    for (int mi = 0; mi < 4; ++mi)
#pragma unroll
      for (int kh = 0; kh < 2; ++kh)
        a0[mi][kh] = read_frag(A1, wm + mi * 16 + lr, kh * 4 + lk);
#pragma unroll
    for (int ni = 0; ni < 2; ++ni)
#pragma unroll
      for (int kh = 0; kh < 2; ++kh)
        bu[ni][kh] = read_frag(B1, wn + ni * 16 + lr, kh * 4 + lk);
    if (!last) stAhi(T + 2);
    SCHED0(); SBAR(); WAIT_LGKM0(); SCHED0();
    __builtin_amdgcn_s_setprio(1);
#pragma unroll
    for (int kh = 0; kh < 2; ++kh)
#pragma unroll
      for (int mi = 0; mi < 4; ++mi)
#pragma unroll
        for (int ni = 0; ni < 2; ++ni)
          au[mi][ni] = MFMA_BF16(a0[mi][kh], bu[ni][kh], au[mi][ni]);
    __builtin_amdgcn_s_setprio(0);
    SCHED0(); SBAR();
    // ph6: read bg(4); stage Bu(T+3); MFMA (m0,g)
#pragma unroll
    for (int ni = 0; ni < 2; ++ni)
#pragma unroll
      for (int kh = 0; kh < 2; ++kh)
        bg[ni][kh] = read_frag(B1, 128 + wn + ni * 16 + lr, kh * 4 + lk);
    if (!last) stBu(T + 3);
    SCHED0(); SBAR(); WAIT_LGKM0(); SCHED0();
    __builtin_amdgcn_s_setprio(1);
#pragma unroll
    for (int kh = 0; kh < 2; ++kh)
#pragma unroll
      for (int mi = 0; mi < 4; ++mi)
#pragma unroll
        for (int ni = 0; ni < 2; ++ni)
          ag[mi][ni] = MFMA_BF16(a0[mi][kh], bg[ni][kh], ag[mi][ni]);
    __builtin_amdgcn_s_setprio(0);
    SCHED0(); SBAR();
    // ph7: read a1(8); stage Bg(T+3); MFMA (m1,u)
#pragma unroll
    for (int mi = 0; mi < 4; ++mi)
#pragma unroll
      for (int kh = 0; kh < 2; ++kh)
        a1[mi][kh] = read_frag(A1, wm + 64 + mi * 16 + lr, kh * 4 + lk);
    if (!last) stBg(T + 3);
    SCHED0(); SBAR(); WAIT_LGKM0(); SCHED0();
    __builtin_amdgcn_s_setprio(1);
#pragma unroll
    for (int kh = 0; kh < 2; ++kh)
#pragma unroll
      for (int mi = 0; mi < 4; ++mi)
#pragma unroll
        for (int ni = 0; ni < 2; ++ni)
          au[4 + mi][ni] = MFMA_BF16(a1[mi][kh], bu[ni][kh], au[4 + mi][ni]);
    __builtin_amdgcn_s_setprio(0);
    SCHED0(); SBAR();
    // ph8: stage A-lo(T+3); vmcnt(6 | 0); MFMA (m1,g)
    if (!last) stAlo(T + 3);
    SCHED0();
    if (last) { WAIT_VM(0); } else { WAIT_VM(6); }
    SBAR(); SCHED0();
    __builtin_amdgcn_s_setprio(1);
#pragma unroll
    for (int kh = 0; kh < 2; ++kh)
#pragma unroll
      for (int mi = 0; mi < 4; ++mi)
#pragma unroll
        for (int ni = 0; ni < 2; ++ni)
          ag[4 + mi][ni] = MFMA_BF16(a1[mi][kh], bg[ni][kh], ag[4 + mi][ni]);
    __builtin_amdgcn_s_setprio(0);
    SCHED0(); SBAR();
  }

  // epilogue: hidden = up * silu(gate); C layout col=lane&15, row=(lane>>4)*4+reg
  unsigned short* He = Hid + ((size_t)e * TTOK + bm * 256) * HDIM + (size_t)bn * 128;
#pragma unroll
  for (int mi = 0; mi < 8; ++mi) {
    int mrow = wm + ((mi < 4) ? mi * 16 : 64 + (mi - 4) * 16);
#pragma unroll
    for (int ni = 0; ni < 2; ++ni)
#pragma unroll
      for (int r = 0; r < 4; ++r) {
        int row = mrow + lk * 4 + r;
        int col = wn + ni * 16 + lr;
        float u = au[mi][ni][r];
        float g = ag[mi][ni][r];
        He[(size_t)row * HDIM + col] = f2bf(u * g / (1.f + __expf(-g)));
      }
  }
}

// ------------- GEMM2: out = hidden @ w_downT, 256x256 tile, m201-faithful 8-phase -------------
// Quadrants: ph1 (m0,n0) | ph2 (m0,n1) | ph3 (m1,n0) | ph4 (m1,n1); same for T+1.
// Stage rolling: ph1: A-lo(T+1) ph2: A-hi(T+1) ph3: B-lo(T+2) ph4: B-hi(T+2)+vm(4)
//                ph5: A-lo(T+2) ph6: A-hi(T+2) ph7: B-lo(T+3) ph8: B-hi(T+3)+vm(4)
__global__ __launch_bounds__(512, 2) void gemm2_down(
    const unsigned short* __restrict__ Hid,
    const unsigned short* __restrict__ WdT,
    float* __restrict__ Out) {
  __shared__ unsigned short sA[2][256 * 64];
  __shared__ unsigned short sB[2][256 * 64];
  const int e = blockIdx.z;
  const int bm = blockIdx.y;   // token tile (256)
  const int bn = blockIdx.x;   // d tile (256)
  const unsigned short* Ae = Hid + ((size_t)e * TTOK + bm * 256) * HDIM;
  const unsigned short* Be = WdT + ((size_t)e * DDIM + (size_t)bn * 256) * HDIM;
  const int tid = threadIdx.x;
  const int lane = tid & 63;
  const int wid = tid >> 6;
  const int wm = (wid & 1) * 128;
  const int wn = (wid >> 1) * 64;
  const int lr = lane & 15;
  const int lk = lane >> 4;

  f32x4 acc[8][4];
#pragma unroll
  for (int i = 0; i < 8; ++i)
#pragma unroll
    for (int j = 0; j < 4; ++j) acc[i][j] = f32x4{0.f, 0.f, 0.f, 0.f};

  auto stAlo = [&](int t) { stage_half(Ae + t * 64, HDIM, (unsigned short*)sA[t & 1], tid); };
  auto stAhi = [&](int t) { stage_half(Ae + (size_t)128 * HDIM + t * 64, HDIM,
                                       (unsigned short*)sA[t & 1] + 128 * 64, tid); };
  auto stBlo = [&](int t) { stage_half(Be + t * 64, HDIM, (unsigned short*)sB[t & 1], tid); };
  auto stBhi = [&](int t) { stage_half(Be + (size_t)128 * HDIM + t * 64, HDIM,
                                       (unsigned short*)sB[t & 1] + 128 * 64, tid); };

  // prologue: tile0 fully, tile1 B-halves (ph1/ph2 of j=0 stage A(1))
  stBlo(0); stBhi(0); stAlo(0); stAhi(0);
  stBlo(1); stBhi(1);
  WAIT_VM(4); SBAR(); SCHED0();

  const int NT = HDIM / 64;   // 64
  for (int j = 0; j < NT / 2; ++j) {
    const int T = 2 * j;
    const bool last = (T + 2 >= NT);
    const unsigned short* A0 = sA[0];
    const unsigned short* B0 = sB[0];
    const unsigned short* A1 = sA[1];
    const unsigned short* B1 = sB[1];
    bf16x8 a0[4][2], a1[4][2], b0[2][2], b1[2][2];

    // ================= K-tile T (buf0) =================
    // ph1: read a0(8), b0(4); stage A-lo(T+1); MFMA (m0,n0)
#pragma unroll
    for (int mi = 0; mi < 4; ++mi)
#pragma unroll
      for (int kh = 0; kh < 2; ++kh)
        a0[mi][kh] = read_frag(A0, wm + mi * 16 + lr, kh * 4 + lk);
#pragma unroll
    for (int ni = 0; ni < 2; ++ni)
#pragma unroll
      for (int kh = 0; kh < 2; ++kh)
        b0[ni][kh] = read_frag(B0, wn + ni * 16 + lr, kh * 4 + lk);
    stAlo(T + 1);
    SCHED0(); SBAR(); WAIT_LGKM0(); SCHED0();
    __builtin_amdgcn_s_setprio(1);
#pragma unroll
    for (int kh = 0; kh < 2; ++kh)
#pragma unroll
      for (int mi = 0; mi < 4; ++mi)
#pragma unroll
        for (int ni = 0; ni < 2; ++ni)
          acc[mi][ni] = MFMA_BF16(a0[mi][kh], b0[ni][kh], acc[mi][ni]);
    __builtin_amdgcn_s_setprio(0);
    SCHED0(); SBAR();
    // ph2: read b1(4); stage A-hi(T+1); MFMA (m0,n1)
#pragma unroll
    for (int ni = 0; ni < 2; ++ni)
#pragma unroll
      for (int kh = 0; kh < 2; ++kh)
        b1[ni][kh] = read_frag(B0, wn + 32 + ni * 16 + lr, kh * 4 + lk);
    stAhi(T + 1);
    SCHED0(); SBAR(); WAIT_LGKM0(); SCHED0();
    __builtin_amdgcn_s_setprio(1);
#pragma unroll
    for (int kh = 0; kh < 2; ++kh)
#pragma unroll
      for (int mi = 0; mi < 4; ++mi)
#pragma unroll
        for (int ni = 0; ni < 2; ++ni)
          acc[mi][2 + ni] = MFMA_BF16(a0[mi][kh], b1[ni][kh], acc[mi][2 + ni]);
    __builtin_amdgcn_s_setprio(0);
    SCHED0(); SBAR();
    // ph3: read a1(8); stage B-lo(T+2); MFMA (m1,n0)
#pragma unroll
    for (int mi = 0; mi < 4; ++mi)
#pragma unroll
      for (int kh = 0; kh < 2; ++kh)
        a1[mi][kh] = read_frag(A0, wm + 64 + mi * 16 + lr, kh * 4 + lk);
    if (!last) stBlo(T + 2);
    SCHED0(); SBAR(); WAIT_LGKM0(); SCHED0();
    __builtin_amdgcn_s_setprio(1);
#pragma unroll
    for (int kh = 0; kh < 2; ++kh)
#pragma unroll
      for (int mi = 0; mi < 4; ++mi)
#pragma unroll
        for (int ni = 0; ni < 2; ++ni)
          acc[4 + mi][ni] = MFMA_BF16(a1[mi][kh], b0[ni][kh], acc[4 + mi][ni]);
    __builtin_amdgcn_s_setprio(0);
    SCHED0(); SBAR();
    // ph4: stage B-hi(T+2); vmcnt(4 | 0); MFMA (m1,n1)
    if (!last) stBhi(T + 2);
    SCHED0();
    if (last) { WAIT_VM(0); } else { WAIT_VM(4); }
    SBAR(); SCHED0();
    __builtin_amdgcn_s_setprio(1);
#pragma unroll
    for (int kh = 0; kh < 2; ++kh)
#pragma unroll
      for (int mi = 0; mi < 4; ++mi)
#pragma unroll
        for (int ni = 0; ni < 2; ++ni)
          acc[4 + mi][2 + ni] = MFMA_BF16(a1[mi][kh], b1[ni][kh], acc[4 + mi][2 + ni]);
    __builtin_amdgcn_s_setprio(0);
    SCHED0(); SBAR();

    // ================= K-tile T+1 (buf1) =================
    // ph5: read a0(8), b0(4); stage A-lo(T+2); MFMA (m0,n0)
#pragma unroll
    for (int mi = 0; mi < 4; ++mi)
#pragma unroll
      for (int kh = 0; kh < 2; ++kh)
        a0[mi][kh] = read_frag(A1, wm + mi * 16 + lr, kh * 4 + lk);
#pragma unroll
    for (int ni = 0; ni < 2; ++ni)
#pragma unroll
      for (int kh = 0; kh < 2; ++kh)
        b0[ni][kh] = read_frag(B1, wn + ni * 16 + lr, kh * 4 + lk);
    if (!last) stAlo(T + 2);
    SCHED0(); SBAR(); WAIT_LGKM0(); SCHED0();
    __builtin_amdgcn_s_setprio(1);
#pragma unroll
    for (int kh = 0; kh < 2; ++kh)
#pragma unroll
      for (int mi = 0; mi < 4; ++mi)
#pragma unroll
        for (int ni = 0; ni < 2; ++ni)
          acc[mi][ni] = MFMA_BF16(a0[mi][kh], b0[ni][kh], acc[mi][ni]);
    __builtin_amdgcn_s_setprio(0);
    SCHED0(); SBAR();
    // ph6: read b1(4); stage A-hi(T+2); MFMA (m0,n1)
#pragma unroll
    for (int ni = 0; ni < 2; ++ni)
#pragma unroll
      for (int kh = 0; kh < 2; ++kh)
        b1[ni][kh] = read_frag(B1, wn + 32 + ni * 16 + lr, kh * 4 + lk);
    if (!last) stAhi(T + 2);
    SCHED0(); SBAR(); WAIT_LGKM0(); SCHED0();
    __builtin_amdgcn_s_setprio(1);
#pragma unroll
    for (int kh = 0; kh < 2; ++kh)
#pragma unroll
      for (int mi = 0; mi < 4; ++mi)
#pragma unroll
        for (int ni = 0; ni < 2; ++ni)
          acc[mi][2 + ni] = MFMA_BF16(a0[mi][kh], b1[ni][kh], acc[mi][2 + ni]);
    __builtin_amdgcn_s_setprio(0);
    SCHED0(); SBAR();
    // ph7: read a1(8); stage B-lo(T+3); MFMA (m1,n0)
#pragma unroll
    for (int mi = 0; mi < 4; ++mi)
#pragma unroll
      for (int kh = 0; kh < 2; ++kh)
        a1[mi][kh] = read_frag(A1, wm + 64 + mi * 16 + lr, kh * 4 + lk);
    if (!last) stBlo(T + 3);
    SCHED0(); SBAR(); WAIT_LGKM0(); SCHED0();
    __builtin_amdgcn_s_setprio(1);
#pragma unroll
    for (int kh = 0; kh < 2; ++kh)
#pragma unroll
      for (int mi = 0; mi < 4; ++mi)
#pragma unroll
        for (int ni = 0; ni < 2; ++ni)
          acc[4 + mi][ni] = MFMA_BF16(a1[mi][kh], b0[ni][kh], acc[4 + mi][ni]);
    __builtin_amdgcn_s_setprio(0);
    SCHED0(); SBAR();
    // ph8: stage B-hi(T+3); vmcnt(4 | 0); MFMA (m1,n1)
    if (!last) stBhi(T + 3);
    SCHED0();
    if (last) { WAIT_VM(0); } else { WAIT_VM(4); }
    SBAR(); SCHED0();
    __builtin_amdgcn_s_setprio(1);
#pragma unroll
    for (int kh = 0; kh < 2; ++kh)
#pragma unroll
      for (int mi = 0; mi < 4; ++mi)
#pragma unroll
        for (int ni = 0; ni < 2; ++ni)
          acc[4 + mi][2 + ni] = MFMA_BF16(a1[mi][kh], b1[ni][kh], acc[4 + mi][2 + ni]);
    __builtin_amdgcn_s_setprio(0);
    SCHED0(); SBAR();
  }

  float* Oe = Out + ((size_t)e * TTOK + bm * 256) * DDIM + (size_t)bn * 256;
#pragma unroll
  for (int mi = 0; mi < 8; ++mi) {
    int mrow = wm + ((mi < 4) ? mi * 16 : 64 + (mi - 4) * 16);
#pragma unroll
    for (int ni = 0; ni < 4; ++ni) {
      int col = wn + ((ni < 2) ? ni * 16 : 32 + (ni - 2) * 16) + lr;
#pragma unroll
      for (int r = 0; r < 4; ++r) {
        int row = mrow + lk * 4 + r;
        Oe[(size_t)row * DDIM + col] = acc[mi][ni][r];
      }
    }
  }
}

extern "C" void kernel_launch(void* const* d_in, const int* in_sizes, int n_in,
                              void* d_out, int out_size, void* d_ws, size_t ws_size,
                              hipStream_t stream) {
  const float* x = (const float*)d_in[0];
  const float* wug = (const float*)d_in[1];
  const float* wd = (const float*)d_in[2];
  float* out = (float*)d_out;

  unsigned short* xb   = (unsigned short*)d_ws;                    // 32768*2048
  unsigned short* wugb = xb   + (size_t)NTOK * DDIM;               // 8*8192*2048
  unsigned short* wdT  = wugb + (size_t)NEXP * 2 * HDIM * DDIM;    // 8*2048*4096
  unsigned short* hid  = wdT  + (size_t)NEXP * DDIM * HDIM;        // 8*4096*4096

  cvt_kernel<<<4096, 256, 0, stream>>>(x, xb, (long)NTOK * DDIM / 4);
  cvt_kernel<<<4096, 256, 0, stream>>>(wug, wugb, (long)NEXP * 2 * HDIM * DDIM / 4);
  transpose_wd<<<dim3(DDIM / 64, HDIM / 64, NEXP), 256, 0, stream>>>(wd, wdT);
  gemm1_swiglu<<<dim3(HDIM / 128, TTOK / 256, NEXP), 512, 0, stream>>>(xb, wugb, hid);
  gemm2_down<<<dim3(DDIM / 256, TTOK / 256, NEXP), 512, 0, stream>>>(hid, wdT, out);
}

// Round 13
// 1767.344 us; speedup vs baseline: 6.5150x; 1.0610x over previous
//
#include <hip/hip_runtime.h>
#include <hip/hip_bf16.h>
#include <cstdint>
#include <cstddef>

// Problem constants: N=32768, D=2048, H=4096, E=8, T = N/E = 4096.
#define NTOK 32768
#define DDIM 2048
#define HDIM 4096
#define NEXP 8
#define TTOK 4096

typedef __attribute__((ext_vector_type(8))) __bf16 bf16x8;
typedef __attribute__((ext_vector_type(4))) float f32x4;

#define MFMA_BF16(a, b, c) __builtin_amdgcn_mfma_f32_16x16x32_bf16((a), (b), (c), 0, 0, 0)
#define SBAR() __builtin_amdgcn_s_barrier()
#define SCHED0() __builtin_amdgcn_sched_barrier(0)
#define WAIT_VM(n) asm volatile("s_waitcnt vmcnt(" #n ")" ::: "memory")
#define WAIT_LGKM0() asm volatile("s_waitcnt lgkmcnt(0)" ::: "memory")

__device__ __forceinline__ unsigned short f2bf(float f) {
  unsigned int u = __builtin_bit_cast(unsigned int, f);
  u += 0x7FFFu + ((u >> 16) & 1u);   // round-to-nearest-even
  return (unsigned short)(u >> 16);
}

// ---------------- f32 -> bf16 convert (vectorized, grid-stride) ----------------
__global__ __launch_bounds__(256) void cvt_kernel(const float* __restrict__ src,
                                                  unsigned short* __restrict__ dst,
                                                  long n4) {
  long i = (long)blockIdx.x * blockDim.x + threadIdx.x;
  long stride = (long)gridDim.x * blockDim.x;
  const float4* s4 = (const float4*)src;
  ushort4* d4 = (ushort4*)dst;
  for (; i < n4; i += stride) {
    float4 v = s4[i];
    ushort4 o;
    o.x = f2bf(v.x); o.y = f2bf(v.y); o.z = f2bf(v.z); o.w = f2bf(v.w);
    d4[i] = o;
  }
}

// ------------- transpose w_down (E,H,D) f32 -> (E,D,H) bf16 -------------
__global__ __launch_bounds__(256) void transpose_wd(const float* __restrict__ w,
                                                    unsigned short* __restrict__ wt) {
  __shared__ unsigned short tile[64][66];
  const int e = blockIdx.z;
  const int h0 = blockIdx.y * 64;
  const int d0 = blockIdx.x * 64;
  const float* we = w + (size_t)e * HDIM * DDIM;
  unsigned short* wte = wt + (size_t)e * DDIM * HDIM;
  const int t = threadIdx.x;
  const int r = t >> 4;
  const int c4 = (t & 15) * 4;
#pragma unroll
  for (int p = 0; p < 4; ++p) {
    int h = r + p * 16;
    float4 v = *(const float4*)(we + (size_t)(h0 + h) * DDIM + d0 + c4);
    tile[h][c4 + 0] = f2bf(v.x);
    tile[h][c4 + 1] = f2bf(v.y);
    tile[h][c4 + 2] = f2bf(v.z);
    tile[h][c4 + 3] = f2bf(v.w);
  }
  __syncthreads();
#pragma unroll
  for (int p = 0; p < 4; ++p) {
    int d = r + p * 16;
    ushort4 o;
    o.x = tile[c4 + 0][d];
    o.y = tile[c4 + 1][d];
    o.z = tile[c4 + 2][d];
    o.w = tile[c4 + 3][d];
    *(ushort4*)(wte + (size_t)(d0 + d) * HDIM + h0 + c4) = o;
  }
}

// ------------- staging: half-tile = 128 rows x 64 bf16, 512 threads x 2 loads -------------
// LDS dest linear; swizzle via inverse-XOR on the GLOBAL source granule (rule #21).
// Proven 0 bank conflicts (rounds 1-12).
__device__ __forceinline__ void stage_half(const unsigned short* __restrict__ g0,
                                           size_t stride_elems,
                                           unsigned short* lds, int tid) {
#pragma unroll
  for (int i = 0; i < 2; ++i) {
    int gi = i * 512 + tid;          // granule 0..1023; r = row 0..127, c = 0..7
    int r = gi >> 3;
    int c = gi & 7;
    const unsigned short* src = g0 + (size_t)r * stride_elems + ((c ^ (r & 7)) << 3);
    __builtin_amdgcn_global_load_lds(
        (const __attribute__((address_space(1))) unsigned int*)src,
        (__attribute__((address_space(3))) unsigned int*)(lds + (size_t)gi * 8),
        16, 0, 0);
  }
}

// ------------- GEMM1 + SwiGLU: r5 structure + static LDS addressing -------------
// 3 phases/K-tile (exact r5 skeleton, 975 us / 52.8% MfmaUtil). NEW: all 24 ds_reads
// use 4 per-wave base pointers (A/B x kh0/kh1) + compile-time offsets; the XOR
// position depends only on (lane, kh) since row&7 == lr&7. K-loop unrolled by 2 so
// the double-buffer select is a static +16384-element offset (max ds offset 55296B).
// Goal: eliminate the per-tile address VALU (VALUBusy 30% -> <20%).
#define G1_TILE(T, BUFE)                                                         \
  {                                                                              \
    if ((T) + 1 < NT) { WAIT_VM(8); } else { WAIT_VM(0); }                       \
    SBAR(); SCHED0();                                                            \
    bf16x8 a0[4][2], a1[4][2], bu[2][2], bg[2][2];                               \
    _Pragma("unroll") for (int mi = 0; mi < 4; ++mi) {                           \
      a0[mi][0] = *(const bf16x8*)(Ak0 + (BUFE) + mi * (16 * 64));               \
      a0[mi][1] = *(const bf16x8*)(Ak1 + (BUFE) + mi * (16 * 64));               \
    }                                                                            \
    _Pragma("unroll") for (int ni = 0; ni < 2; ++ni) {                           \
      bu[ni][0] = *(const bf16x8*)(Bk0 + (BUFE) + ni * (16 * 64));               \
      bu[ni][1] = *(const bf16x8*)(Bk1 + (BUFE) + ni * (16 * 64));               \
      bg[ni][0] = *(const bf16x8*)(Bk0 + (BUFE) + (128 + ni * 16) * 64);         \
      bg[ni][1] = *(const bf16x8*)(Bk1 + (BUFE) + (128 + ni * 16) * 64);         \
    }                                                                            \
    __builtin_amdgcn_s_setprio(1);                                               \
    _Pragma("unroll") for (int kh = 0; kh < 2; ++kh)                             \
      _Pragma("unroll") for (int mi = 0; mi < 4; ++mi)                           \
        _Pragma("unroll") for (int ni = 0; ni < 2; ++ni)                         \
          au[mi][ni] = MFMA_BF16(a0[mi][kh], bu[ni][kh], au[mi][ni]);            \
    __builtin_amdgcn_s_setprio(0);                                               \
    WAIT_LGKM0();                                                                \
    SBAR(); SCHED0();                                                            \
    _Pragma("unroll") for (int mi = 0; mi < 4; ++mi) {                           \
      a1[mi][0] = *(const bf16x8*)(Ak0 + (BUFE) + (64 + mi * 16) * 64);          \
      a1[mi][1] = *(const bf16x8*)(Ak1 + (BUFE) + (64 + mi * 16) * 64);          \
    }                                                                            \
    if ((T) + 2 < NT) { stageB((T) + 2, 0); stageB((T) + 2, 1); }                \
    __builtin_amdgcn_s_setprio(1);                                               \
    _Pragma("unroll") for (int kh = 0; kh < 2; ++kh)                             \
      _Pragma("unroll") for (int mi = 0; mi < 4; ++mi)                           \
        _Pragma("unroll") for (int ni = 0; ni < 2; ++ni)                         \
          ag[mi][ni] = MFMA_BF16(a0[mi][kh], bg[ni][kh], ag[mi][ni]);            \
    __builtin_amdgcn_s_setprio(0);                                               \
    WAIT_LGKM0();                                                                \
    SBAR(); SCHED0();                                                            \
    if ((T) + 2 < NT) { stageA((T) + 2, 0); stageA((T) + 2, 1); }                \
    __builtin_amdgcn_s_setprio(1);                                               \
    _Pragma("unroll") for (int kh = 0; kh < 2; ++kh)                             \
      _Pragma("unroll") for (int mi = 0; mi < 4; ++mi)                           \
        _Pragma("unroll") for (int ni = 0; ni < 2; ++ni) {                       \
          au[4 + mi][ni] = MFMA_BF16(a1[mi][kh], bu[ni][kh], au[4 + mi][ni]);    \
          ag[4 + mi][ni] = MFMA_BF16(a1[mi][kh], bg[ni][kh], ag[4 + mi][ni]);    \
        }                                                                        \
    __builtin_amdgcn_s_setprio(0);                                               \
  }

__global__ __launch_bounds__(512, 2) void gemm1_swiglu(
    const unsigned short* __restrict__ Xb,
    const unsigned short* __restrict__ Wb,
    unsigned short* __restrict__ Hid) {
  __shared__ unsigned short sA[2][256 * 64];   // 64 KiB (x rows)
  __shared__ unsigned short sB[2][256 * 64];   // 64 KiB [u 0-127 ; g 128-255]
  const int e = blockIdx.z;
  const int bm = blockIdx.y;   // token tile (256)
  const int bn = blockIdx.x;   // h tile (128)
  const unsigned short* Xe = Xb + ((size_t)e * TTOK + bm * 256) * DDIM;
  const unsigned short* Wu = Wb + ((size_t)e * 2 * HDIM + (size_t)bn * 128) * DDIM;
  const unsigned short* Wg = Wu + (size_t)HDIM * DDIM;
  const int tid = threadIdx.x;
  const int lane = tid & 63;
  const int wid = tid >> 6;
  const int wm = (wid & 1) * 128;   // M-half rows
  const int wn = (wid >> 1) * 32;   // h cols within 128
  const int lr = lane & 15;
  const int lk = lane >> 4;

  // per-wave LDS base pointers; all reads are base + compile-time offset
  const int p0 = (lk ^ (lr & 7)) << 3;         // kh=0 granule position (elems)
  const int p1 = ((4 + lk) ^ (lr & 7)) << 3;   // kh=1
  const unsigned short* Ak0 = &sA[0][(wm + lr) * 64] + p0;
  const unsigned short* Ak1 = &sA[0][(wm + lr) * 64] + p1;
  const unsigned short* Bk0 = &sB[0][(wn + lr) * 64] + p0;
  const unsigned short* Bk1 = &sB[0][(wn + lr) * 64] + p1;

  f32x4 au[8][2], ag[8][2];
#pragma unroll
  for (int i = 0; i < 8; ++i)
#pragma unroll
    for (int j = 0; j < 2; ++j) {
      au[i][j] = f32x4{0.f, 0.f, 0.f, 0.f};
      ag[i][j] = f32x4{0.f, 0.f, 0.f, 0.f};
    }

  auto stageA = [&](int t, int half) {
    stage_half(Xe + (size_t)(half * 128) * DDIM + t * 64, DDIM,
               (unsigned short*)sA[t & 1] + half * (128 * 64), tid);
  };
  auto stageB = [&](int t, int half) {   // half0 = up rows, half1 = gate rows
    stage_half((half ? Wg : Wu) + t * 64, DDIM,
               (unsigned short*)sB[t & 1] + half * (128 * 64), tid);
  };

  // prologue: tiles 0 and 1 (8 loads/thread each)
  stageB(0, 0); stageB(0, 1); stageA(0, 0); stageA(0, 1);
  stageB(1, 0); stageB(1, 1); stageA(1, 0); stageA(1, 1);

  const int NT = DDIM / 64;   // 32
  for (int tt = 0; tt < NT; tt += 2) {
    G1_TILE(tt, 0);
    G1_TILE(tt + 1, 16384);   // buf1 = +256*64 elements (static ds offset +32768B)
  }

  // epilogue: hidden = up * silu(gate); C layout col=lane&15, row=(lane>>4)*4+reg
  unsigned short* He = Hid + ((size_t)e * TTOK + bm * 256) * HDIM + (size_t)bn * 128;
#pragma unroll
  for (int mi = 0; mi < 8; ++mi) {
    int mrow = wm + ((mi < 4) ? mi * 16 : 64 + (mi - 4) * 16);
#pragma unroll
    for (int ni = 0; ni < 2; ++ni)
#pragma unroll
      for (int r = 0; r < 4; ++r) {
        int row = mrow + lk * 4 + r;
        int col = wn + ni * 16 + lr;
        float u = au[mi][ni][r];
        float g = ag[mi][ni][r];
        He[(size_t)row * HDIM + col] = f2bf(u * g / (1.f + __expf(-g)));
      }
  }
}

// ------------- GEMM2: out = hidden @ w_downT, 256x256, r5 structure + static addressing -------------
#define G2_TILE(T, BUFE)                                                         \
  {                                                                              \
    if ((T) + 1 < NT) { WAIT_VM(8); } else { WAIT_VM(0); }                       \
    SBAR(); SCHED0();                                                            \
    bf16x8 a0[4][2], a1[4][2], b0[2][2], b1[2][2];                               \
    _Pragma("unroll") for (int mi = 0; mi < 4; ++mi) {                           \
      a0[mi][0] = *(const bf16x8*)(Ak0 + (BUFE) + mi * (16 * 64));               \
      a0[mi][1] = *(const bf16x8*)(Ak1 + (BUFE) + mi * (16 * 64));               \
    }                                                                            \
    _Pragma("unroll") for (int ni = 0; ni < 2; ++ni) {                           \
      b0[ni][0] = *(const bf16x8*)(Bk0 + (BUFE) + ni * (16 * 64));               \
      b0[ni][1] = *(const bf16x8*)(Bk1 + (BUFE) + ni * (16 * 64));               \
      b1[ni][0] = *(const bf16x8*)(Bk0 + (BUFE) + (32 + ni * 16) * 64);          \
      b1[ni][1] = *(const bf16x8*)(Bk1 + (BUFE) + (32 + ni * 16) * 64);          \
    }                                                                            \
    __builtin_amdgcn_s_setprio(1);                                               \
    _Pragma("unroll") for (int kh = 0; kh < 2; ++kh)                             \
      _Pragma("unroll") for (int mi = 0; mi < 4; ++mi)                           \
        _Pragma("unroll") for (int ni = 0; ni < 2; ++ni)                         \
          acc[mi][ni] = MFMA_BF16(a0[mi][kh], b0[ni][kh], acc[mi][ni]);          \
    __builtin_amdgcn_s_setprio(0);                                               \
    WAIT_LGKM0();                                                                \
    SBAR(); SCHED0();                                                            \
    _Pragma("unroll") for (int mi = 0; mi < 4; ++mi) {                           \
      a1[mi][0] = *(const bf16x8*)(Ak0 + (BUFE) + (64 + mi * 16) * 64);          \
      a1[mi][1] = *(const bf16x8*)(Ak1 + (BUFE) + (64 + mi * 16) * 64);          \
    }                                                                            \
    if ((T) + 2 < NT) { stageB((T) + 2, 0); stageB((T) + 2, 1); }                \
    __builtin_amdgcn_s_setprio(1);                                               \
    _Pragma("unroll") for (int kh = 0; kh < 2; ++kh)                             \
      _Pragma("unroll") for (int mi = 0; mi < 4; ++mi)                           \
        _Pragma("unroll") for (int ni = 0; ni < 2; ++ni)                         \
          acc[mi][2 + ni] = MFMA_BF16(a0[mi][kh], b1[ni][kh], acc[mi][2 + ni]);  \
    __builtin_amdgcn_s_setprio(0);                                               \
    WAIT_LGKM0();                                                                \
    SBAR(); SCHED0();                                                            \
    if ((T) + 2 < NT) { stageA((T) + 2, 0); stageA((T) + 2, 1); }                \
    __builtin_amdgcn_s_setprio(1);                                               \
    _Pragma("unroll") for (int kh = 0; kh < 2; ++kh)                             \
      _Pragma("unroll") for (int mi = 0; mi < 4; ++mi)                           \
        _Pragma("unroll") for (int ni = 0; ni < 2; ++ni) {                       \
          acc[4 + mi][ni] = MFMA_BF16(a1[mi][kh], b0[ni][kh], acc[4 + mi][ni]);  \
          acc[4 + mi][2 + ni] = MFMA_BF16(a1[mi][kh], b1[ni][kh], acc[4 + mi][2 + ni]); \
        }                                                                        \
    __builtin_amdgcn_s_setprio(0);                                               \
  }

__global__ __launch_bounds__(512, 2) void gemm2_down(
    const unsigned short* __restrict__ Hid,
    const unsigned short* __restrict__ WdT,
    float* __restrict__ Out) {
  __shared__ unsigned short sA[2][256 * 64];
  __shared__ unsigned short sB[2][256 * 64];
  const int e = blockIdx.z;
  const int bm = blockIdx.y;   // token tile (256)
  const int bn = blockIdx.x;   // d tile (256)
  const unsigned short* Ae = Hid + ((size_t)e * TTOK + bm * 256) * HDIM;
  const unsigned short* Be = WdT + ((size_t)e * DDIM + (size_t)bn * 256) * HDIM;
  const int tid = threadIdx.x;
  const int lane = tid & 63;
  const int wid = tid >> 6;
  const int wm = (wid & 1) * 128;
  const int wn = (wid >> 1) * 64;
  const int lr = lane & 15;
  const int lk = lane >> 4;

  const int p0 = (lk ^ (lr & 7)) << 3;
  const int p1 = ((4 + lk) ^ (lr & 7)) << 3;
  const unsigned short* Ak0 = &sA[0][(wm + lr) * 64] + p0;
  const unsigned short* Ak1 = &sA[0][(wm + lr) * 64] + p1;
  const unsigned short* Bk0 = &sB[0][(wn + lr) * 64] + p0;
  const unsigned short* Bk1 = &sB[0][(wn + lr) * 64] + p1;

  f32x4 acc[8][4];
#pragma unroll
  for (int i = 0; i < 8; ++i)
#pragma unroll
    for (int j = 0; j < 4; ++j) acc[i][j] = f32x4{0.f, 0.f, 0.f, 0.f};

  auto stageA = [&](int t, int half) {
    stage_half(Ae + (size_t)(half * 128) * HDIM + t * 64, HDIM,
               (unsigned short*)sA[t & 1] + half * (128 * 64), tid);
  };
  auto stageB = [&](int t, int half) {
    stage_half(Be + (size_t)(half * 128) * HDIM + t * 64, HDIM,
               (unsigned short*)sB[t & 1] + half * (128 * 64), tid);
  };

  stageB(0, 0); stageB(0, 1); stageA(0, 0); stageA(0, 1);
  stageB(1, 0); stageB(1, 1); stageA(1, 0); stageA(1, 1);

  const int NT = HDIM / 64;   // 64
  for (int tt = 0; tt < NT; tt += 2) {
    G2_TILE(tt, 0);
    G2_TILE(tt + 1, 16384);
  }

  float* Oe = Out + ((size_t)e * TTOK + bm * 256) * DDIM + (size_t)bn * 256;
#pragma unroll
  for (int mi = 0; mi < 8; ++mi) {
    int mrow = wm + ((mi < 4) ? mi * 16 : 64 + (mi - 4) * 16);
#pragma unroll
    for (int ni = 0; ni < 4; ++ni) {
      int col = wn + ((ni < 2) ? ni * 16 : 32 + (ni - 2) * 16) + lr;
#pragma unroll
      for (int r = 0; r < 4; ++r) {
        int row = mrow + lk * 4 + r;
        Oe[(size_t)row * DDIM + col] = acc[mi][ni][r];
      }
    }
  }
}

extern "C" void kernel_launch(void* const* d_in, const int* in_sizes, int n_in,
                              void* d_out, int out_size, void* d_ws, size_t ws_size,
                              hipStream_t stream) {
  const float* x = (const float*)d_in[0];
  const float* wug = (const float*)d_in[1];
  const float* wd = (const float*)d_in[2];
  float* out = (float*)d_out;

  unsigned short* xb   = (unsigned short*)d_ws;                    // 32768*2048
  unsigned short* wugb = xb   + (size_t)NTOK * DDIM;               // 8*8192*2048
  unsigned short* wdT  = wugb + (size_t)NEXP * 2 * HDIM * DDIM;    // 8*2048*4096
  unsigned short* hid  = wdT  + (size_t)NEXP * DDIM * HDIM;        // 8*4096*4096

  cvt_kernel<<<4096, 256, 0, stream>>>(x, xb, (long)NTOK * DDIM / 4);
  cvt_kernel<<<4096, 256, 0, stream>>>(wug, wugb, (long)NEXP * 2 * HDIM * DDIM / 4);
  transpose_wd<<<dim3(DDIM / 64, HDIM / 64, NEXP), 256, 0, stream>>>(wd, wdT);
  gemm1_swiglu<<<dim3(HDIM / 128, TTOK / 256, NEXP), 512, 0, stream>>>(xb, wugb, hid);
  gemm2_down<<<dim3(DDIM / 256, TTOK / 256, NEXP), 512, 0, stream>>>(hid, wdT, out);
}